// Round 3
// baseline (49726.804 us; speedup 1.0000x reference)
//
#include <hip/hip_runtime.h>
#include <cstdint>
#include <cstddef>

// 4-layer projected LSTM. B=64 T=256 D=512 H=1024 P=256.
// Inputs fp32, output fp32 (verified round 2). Tolerance floor is 8*bf16-eps,
// but plain-bf16 MFMA rounding accumulated ~3e-3 over the 1024-step
// recurrence -> use split-bf16 (hi+lo) operands with 3 MFMAs per product
// (hi*hi + hi*lo + lo*hi); dropped lo*lo term is ~2^-18 relative.
//
// Structure: one cooperative persistent kernel, 128 WGs x 128 threads.
//  - WG w owns 8 hidden units (32 gate rows). [32 x (Din+256)] weight slice,
//    split hi/lo, staged in LDS once per layer (~99 KB), reused 256 steps.
//  - Phase 1 (all WGs): gates via mfma_32x32x16_bf16 x3 -> sG -> fp32 gate
//    math, c-state in registers, h -> hbuf hi/lo planes. Grid barrier.
//  - Phase 2 (WGs 0..63, wave 0): y_t = h @ W_hr^T via mfma_16x16x32_bf16 x3,
//    W_hr hi/lo pre-staged to workspace per layer. Writes y[t] IN PLACE
//    (single y buffer: layer l reads y[t] (= layer l-1's) in phase 1, then
//    overwrites it in phase 2 -- ordered by the grid barrier). Grid barrier.
// Round-2 bug fixed: previous yA/yB ping-pong under-allocated (4 MB spacing
// for 8 MB buffers) -> overlap corruption for t>=128 on odd layers.
//
// Workspace: [cnt 1K][yH 8M][yL 8M][whrH 512K][whrL 512K][hH 128K][hL 128K]
//   = 17.3 MB.

#define B_ 64
#define T_ 256
#define D_ 512
#define H_ 1024
#define P_ 256
#define NWG 128
#define NTHR 128
#define UPW 8
#define WSTRIDE 776    // 768 + 8 pad (16B-aligned rows)

using short8  = __attribute__((ext_vector_type(8))) short;
using short4v = __attribute__((ext_vector_type(4))) short;
using f32x16  = __attribute__((ext_vector_type(16))) float;
using f32x4   = __attribute__((ext_vector_type(4))) float;

__device__ inline float bf2f(short s) {
  unsigned u = ((unsigned)(unsigned short)s) << 16;
  return __builtin_bit_cast(float, u);
}
__device__ inline unsigned short f2bf(float f) {
  unsigned u = __builtin_bit_cast(unsigned, f);
  u += 0x7fffu + ((u >> 16) & 1u);   // RTNE
  return (unsigned short)(u >> 16);
}
__device__ inline void split1(float v, short& hi, short& lo) {
  unsigned short h = f2bf(v);
  hi = (short)h;
  lo = (short)f2bf(v - bf2f((short)h));
}
__device__ inline void split8(const float* p, short8& hi, short8& lo) {
  float4 a = *(const float4*)p;
  float4 b = *(const float4*)(p + 4);
  float v[8] = {a.x, a.y, a.z, a.w, b.x, b.y, b.z, b.w};
#pragma unroll
  for (int i = 0; i < 8; ++i) {
    short h, l;
    split1(v[i], h, l);
    hi[i] = h; lo[i] = l;
  }
}
__device__ inline float sigm(float x)   { return 1.f / (1.f + __expf(-x)); }
__device__ inline float tanh_f(float x) { return 1.f - 2.f / (__expf(2.f * x) + 1.f); }

__device__ inline void gbar(unsigned* cnt, unsigned target) {
  __threadfence();
  __syncthreads();
  if (threadIdx.x == 0) {
    __hip_atomic_fetch_add(cnt, 1u, __ATOMIC_RELEASE, __HIP_MEMORY_SCOPE_AGENT);
    while (__hip_atomic_load(cnt, __ATOMIC_ACQUIRE, __HIP_MEMORY_SCOPE_AGENT) < target)
      __builtin_amdgcn_s_sleep(1);
  }
  __syncthreads();
  __threadfence();
}

__global__ __launch_bounds__(NTHR) void lstm_kernel(
    const float* __restrict__ x,
    const float* __restrict__ Wih0, const float* __restrict__ Whh0,
    const float* __restrict__ bih0, const float* __restrict__ bhh0,
    const float* __restrict__ Whr0,
    const float* __restrict__ Wihs, const float* __restrict__ Whhs,
    const float* __restrict__ bihs, const float* __restrict__ bhhs,
    const float* __restrict__ Whrs,
    float* __restrict__ out,
    short* __restrict__ yH, short* __restrict__ yL,
    short* __restrict__ whrH, short* __restrict__ whrL,
    short* __restrict__ hH, short* __restrict__ hL,
    unsigned* __restrict__ cnt)
{
  __shared__ short sWh[32 * WSTRIDE];   // 49664 B
  __shared__ short sWl[32 * WSTRIDE];   // 49664 B
  __shared__ float sBias[32];
  __shared__ float sG[64 * 32];         // 8192 B

  const int tid  = threadIdx.x;
  const int wg   = blockIdx.x;
  const int lane = tid & 63;
  const int wave = tid >> 6;
  unsigned ep = 0;

  // mfma_f32_32x32x16_bf16 lane geometry:
  //   A[m][k]: m = lane&31 (+ wave*32 tile), k = (lane>>5)*8 + j
  //   B[k][n] = W[n][k]: n = lane&31, same k split
  //   D: col = lane&31, row = (reg&3) + 8*(reg>>2) + 4*(lane>>5)
  const int m1  = wave * 32 + (lane & 31);  // batch row
  const int n1  = lane & 31;                // local gate row
  const int kh1 = (lane >> 5) * 8;

  for (int l = 0; l < 4; ++l) {
    const int K1 = (l == 0) ? D_ : P_;
    const float* Wih = (l == 0) ? Wih0 : Wihs + (size_t)(l - 1) * 4096 * 256;
    const float* Whh = (l == 0) ? Whh0 : Whhs + (size_t)(l - 1) * 4096 * 256;
    const float* bih = (l == 0) ? bih0 : bihs + (size_t)(l - 1) * 4096;
    const float* bhh = (l == 0) ? bhh0 : bhhs + (size_t)(l - 1) * 4096;
    const float* Whr = (l == 0) ? Whr0 : Whrs + (size_t)(l - 1) * 256 * 1024;

    // ---- stage weight slice (split hi/lo) + bias into LDS ----
    {
      const int cpr = (K1 + P_) >> 3;   // 8-elem chunks per row
      for (int c = tid; c < 32 * cpr; c += NTHR) {
        int r = c / cpr;
        int k = (c - r * cpr) * 8;
        int R = (r & 3) * H_ + wg * UPW + (r >> 2);   // gate*H + unit
        const float* src = (k < K1) ? (Wih + (size_t)R * K1 + k)
                                    : (Whh + (size_t)R * P_ + (k - K1));
        short8 hi, lo;
        split8(src, hi, lo);
        *(short8*)&sWh[r * WSTRIDE + k] = hi;
        *(short8*)&sWl[r * WSTRIDE + k] = lo;
      }
      if (tid < 32) {
        int r = tid;
        int R = (r & 3) * H_ + wg * UPW + (r >> 2);
        sBias[r] = bih[R] + bhh[R];
      }
      // stage W_hr (split hi/lo) into workspace, whole grid cooperates
      for (int c = wg * NTHR + tid; c < (P_ * H_) >> 3; c += NWG * NTHR) {
        short8 hi, lo;
        split8(Whr + (size_t)c * 8, hi, lo);
        *(short8*)&whrH[(size_t)c * 8] = hi;
        *(short8*)&whrL[(size_t)c * 8] = lo;
      }
      __syncthreads();
    }

    // c-state: thread handles batch b = tid>>1, units u4..u4+3
    float cs0 = 0.f, cs1 = 0.f, cs2 = 0.f, cs3 = 0.f;

    for (int t = 0; t < T_; ++t) {
      // ================= phase 1: gates + state update =================
      f32x16 acc = {};
      {
        const short* bwh = &sWh[n1 * WSTRIDE + kh1];
        const short* bwl = &sWl[n1 * WSTRIDE + kh1];
        if (l == 0) {
          const float* axf = x + ((size_t)m1 * T_ + t) * D_ + kh1;
#pragma unroll 4
          for (int k0 = 0; k0 < D_; k0 += 16) {
            short8 ah, al;
            split8(axf + k0, ah, al);
            short8 bh = *(const short8*)(bwh + k0);
            short8 bl = *(const short8*)(bwl + k0);
            acc = __builtin_amdgcn_mfma_f32_32x32x16_bf16(ah, bh, acc, 0, 0, 0);
            acc = __builtin_amdgcn_mfma_f32_32x32x16_bf16(ah, bl, acc, 0, 0, 0);
            acc = __builtin_amdgcn_mfma_f32_32x32x16_bf16(al, bh, acc, 0, 0, 0);
          }
        } else {
          const size_t base = ((size_t)t * B_ + m1) * P_ + kh1;
#pragma unroll 4
          for (int k0 = 0; k0 < P_; k0 += 16) {
            short8 ah = *(const short8*)&yH[base + k0];
            short8 al = *(const short8*)&yL[base + k0];
            short8 bh = *(const short8*)(bwh + k0);
            short8 bl = *(const short8*)(bwl + k0);
            acc = __builtin_amdgcn_mfma_f32_32x32x16_bf16(ah, bh, acc, 0, 0, 0);
            acc = __builtin_amdgcn_mfma_f32_32x32x16_bf16(ah, bl, acc, 0, 0, 0);
            acc = __builtin_amdgcn_mfma_f32_32x32x16_bf16(al, bh, acc, 0, 0, 0);
          }
        }
        if (t > 0) {   // recurrent hp = y[t-1] (this layer's own output)
          const size_t rb = ((size_t)(t - 1) * B_ + m1) * P_ + kh1;
          const short* bhh_h = bwh + K1;
          const short* bhh_l = bwl + K1;
#pragma unroll 4
          for (int k0 = 0; k0 < P_; k0 += 16) {
            short8 ah = *(const short8*)&yH[rb + k0];
            short8 al = *(const short8*)&yL[rb + k0];
            short8 bh = *(const short8*)(bhh_h + k0);
            short8 bl = *(const short8*)(bhh_l + k0);
            acc = __builtin_amdgcn_mfma_f32_32x32x16_bf16(ah, bh, acc, 0, 0, 0);
            acc = __builtin_amdgcn_mfma_f32_32x32x16_bf16(ah, bl, acc, 0, 0, 0);
            acc = __builtin_amdgcn_mfma_f32_32x32x16_bf16(al, bh, acc, 0, 0, 0);
          }
        }
      }
#pragma unroll
      for (int r = 0; r < 16; ++r) {
        int mrow = (r & 3) + 8 * (r >> 2) + 4 * (lane >> 5) + wave * 32;
        sG[mrow * 32 + n1] = acc[r];
      }
      __syncthreads();
      {
        const int b  = tid >> 1;
        const int u4 = (tid & 1) * 4;
        const float* gp = &sG[b * 32];
        float cr[4] = {cs0, cs1, cs2, cs3};
        short4v hhi, hlo;
#pragma unroll
        for (int j = 0; j < 4; ++j) {
          int u = u4 + j;
          float ii = sigm(gp[u * 4 + 0] + sBias[u * 4 + 0]);
          float ff = sigm(gp[u * 4 + 1] + sBias[u * 4 + 1]);
          float gg = tanh_f(gp[u * 4 + 2] + sBias[u * 4 + 2]);
          float oo = sigm(gp[u * 4 + 3] + sBias[u * 4 + 3]);
          float cv = ff * cr[j] + ii * gg;
          cr[j] = cv;
          float hv = oo * tanh_f(cv);
          short h, lo2;
          split1(hv, h, lo2);
          hhi[j] = h; hlo[j] = lo2;
        }
        cs0 = cr[0]; cs1 = cr[1]; cs2 = cr[2]; cs3 = cr[3];
        size_t ho = (size_t)b * H_ + wg * UPW + u4;
        *(short4v*)&hH[ho] = hhi;
        *(short4v*)&hL[ho] = hlo;
      }
      ep++; gbar(cnt, NWG * ep);

      // ================= phase 2: projection y_t = h @ W_hr^T ==========
      // mfma_f32_16x16x32_bf16: A m = lane&15, k = (lane>>4)*8 + j;
      // B n = lane&15 (row of W_hr), same k; D col = lane&15, row = quad*4+reg.
      if (wg < 64 && wave == 0) {
        const int m0  = (wg >> 4) * 16;
        const int n0  = (wg & 15) * 16;
        const int l16 = lane & 15;
        const int kh2 = (lane >> 4) * 8;
        const short* ahh = hH + (size_t)(m0 + l16) * H_ + kh2;
        const short* ahl = hL + (size_t)(m0 + l16) * H_ + kh2;
        const short* bwh = whrH + (size_t)(n0 + l16) * H_ + kh2;
        const short* bwl = whrL + (size_t)(n0 + l16) * H_ + kh2;
        f32x4 a4 = {};
#pragma unroll 4
        for (int k0 = 0; k0 < H_; k0 += 32) {
          short8 Ah = *(const short8*)(ahh + k0);
          short8 Al = *(const short8*)(ahl + k0);
          short8 Bh = *(const short8*)(bwh + k0);
          short8 Bl = *(const short8*)(bwl + k0);
          a4 = __builtin_amdgcn_mfma_f32_16x16x32_bf16(Ah, Bh, a4, 0, 0, 0);
          a4 = __builtin_amdgcn_mfma_f32_16x16x32_bf16(Ah, Bl, a4, 0, 0, 0);
          a4 = __builtin_amdgcn_mfma_f32_16x16x32_bf16(Al, Bh, a4, 0, 0, 0);
        }
#pragma unroll
        for (int r = 0; r < 4; ++r) {
          int mm  = m0 + (lane >> 4) * 4 + r;
          int col = n0 + l16;
          float v = a4[r];
          short h, lo2;
          split1(v, h, lo2);
          size_t oy = ((size_t)t * B_ + mm) * P_ + col;
          yH[oy] = h;
          yL[oy] = lo2;
          if (l == 3 && t == T_ - 1) out[mm * P_ + col] = v;
        }
      }
      ep++; gbar(cnt, NWG * ep);
    }
  }
}

extern "C" void kernel_launch(void* const* d_in, const int* in_sizes, int n_in,
                              void* d_out, int out_size, void* d_ws, size_t ws_size,
                              hipStream_t stream) {
  const float* x    = (const float*)d_in[0];
  const float* Wih0 = (const float*)d_in[1];
  const float* Whh0 = (const float*)d_in[2];
  const float* bih0 = (const float*)d_in[3];
  const float* bhh0 = (const float*)d_in[4];
  const float* Whr0 = (const float*)d_in[5];
  const float* Wihs = (const float*)d_in[6];
  const float* Whhs = (const float*)d_in[7];
  const float* bihs = (const float*)d_in[8];
  const float* bhhs = (const float*)d_in[9];
  const float* Whrs = (const float*)d_in[10];
  float* out = (float*)d_out;

  char* ws = (char*)d_ws;
  unsigned* cnt = (unsigned*)ws;                         // 1 KB
  short* yH   = (short*)(ws + 1024);                     // 8 MB (T*B*P)
  short* yL   = (short*)(ws + 1024 + 8388608);           // 8 MB
  short* whrH = (short*)(ws + 1024 + 16777216);          // 512 KB (P*H)
  short* whrL = (short*)(ws + 1024 + 16777216 + 524288); // 512 KB
  short* hH   = (short*)(ws + 1024 + 16777216 + 1048576);           // 128 KB (B*H)
  short* hL   = (short*)(ws + 1024 + 16777216 + 1048576 + 131072);  // 128 KB

  hipMemsetAsync(d_ws, 0, 256, stream);   // zero barrier counter

  void* args[] = {&x, &Wih0, &Whh0, &bih0, &bhh0, &Whr0,
                  &Wihs, &Whhs, &bihs, &bhhs, &Whrs,
                  &out, &yH, &yL, &whrH, &whrL, &hH, &hL, &cnt};
  hipLaunchCooperativeKernel((void*)lstm_kernel, dim3(NWG), dim3(NTHR),
                             args, 0, stream);
}

// Round 5
// 28727.753 us; speedup vs baseline: 1.7310x; 1.7310x over previous
//
#include <hip/hip_runtime.h>
#include <cstdint>
#include <cstddef>

// 4-layer projected LSTM. B=64 T=256 D=512 H=1024 P=256. fp32 in/out.
// Split-bf16 (hi+lo) MFMA operands, 3 MFMAs per product (round-3: absmax 6e-5).
//
// Round-4/5: fence-free cross-XCD coherence.
//  - Round-3 spent 24 us/epoch: acquire-polling + __threadfence flushed the
//    per-XCD L2 thousands of times per step (FETCH 1.7 GB vs 75 MB inputs).
//  - Now: shared mutable state (y, h) packed u32 = bf16hi | bf16lo<<16,
//    accessed ONLY via relaxed agent-scope atomics (sc1: bypass L1/L2, live
//    at L3). No dirty lines -> no wbl2; no cached copies -> no inv.
//  - Read-only inputs (x, Wih, Whh, biases, Whr) use normal cached loads;
//    L2 stays warm across all 1024 steps. Whr split hi/lo on the fly (VALU
//    was 0.9% busy).
//  - Exception: phase-1 input read of y[t] (written by layer l-1, ordered
//    by hundreds of barriers ago) is normal-cached; ONE __threadfence per
//    layer (4 total) kills possible stale lines. (Round-4 compile fix:
//    __hip_atomic_thread_fence doesn't exist in this ROCm; __threadfence
//    is the available full agent-scope fence, fine at 4 uses/kernel.)
//  - Barrier: syncthreads -> relaxed add -> relaxed poll -> syncthreads.
//    __syncthreads drains vmcnt => sc1 stores globally visible before add.
//
// Structure (unchanged): 128 WGs x 128 thr cooperative persistent kernel.
//  Phase 1 (all WGs): gates via mfma_32x32x16_bf16 x3, weights hi/lo in LDS
//  (staged once per layer), fp32 gate math, c in regs, h -> hP (packed sc1).
//  Barrier. Phase 2 (WGs 0..63 wave 0): y_t = h @ Whr^T via mfma_16x16x32 x3,
//  y[t] overwritten in place (barrier-ordered). Barrier.
// Workspace: [cnt 1K][yP 16M][hP 256K] ~= 16.3 MB.

#define B_ 64
#define T_ 256
#define D_ 512
#define H_ 1024
#define P_ 256
#define NWG 128
#define NTHR 128
#define UPW 8
#define WSTRIDE 776    // 768 + 8 pad (16B-aligned rows)

using short8  = __attribute__((ext_vector_type(8))) short;
using f32x16  = __attribute__((ext_vector_type(16))) float;
using f32x4   = __attribute__((ext_vector_type(4))) float;

__device__ inline float bf2f(short s) {
  unsigned u = ((unsigned)(unsigned short)s) << 16;
  return __builtin_bit_cast(float, u);
}
__device__ inline unsigned short f2bf(float f) {
  unsigned u = __builtin_bit_cast(unsigned, f);
  u += 0x7fffu + ((u >> 16) & 1u);   // RTNE
  return (unsigned short)(u >> 16);
}
__device__ inline void split1(float v, short& hi, short& lo) {
  unsigned short h = f2bf(v);
  hi = (short)h;
  lo = (short)f2bf(v - bf2f((short)h));
}
__device__ inline unsigned packf(float v) {
  short h, l;
  split1(v, h, l);
  return (unsigned)(unsigned short)h | ((unsigned)(unsigned short)l << 16);
}
__device__ inline void split8(const float* p, short8& hi, short8& lo) {
  float4 a = *(const float4*)p;
  float4 b = *(const float4*)(p + 4);
  float v[8] = {a.x, a.y, a.z, a.w, b.x, b.y, b.z, b.w};
#pragma unroll
  for (int i = 0; i < 8; ++i) {
    short h, l;
    split1(v[i], h, l);
    hi[i] = h; lo[i] = l;
  }
}
// 8 packed elems via normal cached loads (read-only-within-layer data)
__device__ inline void unpack_c8(const unsigned* p, short8& hi, short8& lo) {
  uint4 a = *(const uint4*)p;
  uint4 b = *(const uint4*)(p + 4);
  unsigned w[8] = {a.x, a.y, a.z, a.w, b.x, b.y, b.z, b.w};
#pragma unroll
  for (int i = 0; i < 8; ++i) {
    hi[i] = (short)(w[i] & 0xffff);
    lo[i] = (short)(w[i] >> 16);
  }
}
// 8 packed elems via sc1 (agent-coherent) loads — for per-step mutable data
__device__ inline void unpack_a8(const unsigned* p, short8& hi, short8& lo) {
#pragma unroll
  for (int i = 0; i < 4; ++i) {
    unsigned long long v = __hip_atomic_load((const unsigned long long*)p + i,
                                             __ATOMIC_RELAXED, __HIP_MEMORY_SCOPE_AGENT);
    unsigned w0 = (unsigned)v, w1 = (unsigned)(v >> 32);
    hi[2 * i]     = (short)(w0 & 0xffff);
    lo[2 * i]     = (short)(w0 >> 16);
    hi[2 * i + 1] = (short)(w1 & 0xffff);
    lo[2 * i + 1] = (short)(w1 >> 16);
  }
}
__device__ inline float sigm(float x)   { return 1.f / (1.f + __expf(-x)); }
__device__ inline float tanh_f(float x) { return 1.f - 2.f / (__expf(2.f * x) + 1.f); }

// Fence-free grid barrier: relaxed add + relaxed poll (sc1, served at L3).
// No buffer_wbl2 / buffer_inv — the L2s stay warm.
__device__ inline void gbar(unsigned* cnt, unsigned target) {
  __syncthreads();   // drains vmcnt: all sc1 stores globally visible
  if (threadIdx.x == 0) {
    __hip_atomic_fetch_add(cnt, 1u, __ATOMIC_RELAXED, __HIP_MEMORY_SCOPE_AGENT);
    while (__hip_atomic_load(cnt, __ATOMIC_RELAXED, __HIP_MEMORY_SCOPE_AGENT) < target)
      __builtin_amdgcn_s_sleep(4);
  }
  __syncthreads();
}

__global__ __launch_bounds__(NTHR) void lstm_kernel(
    const float* __restrict__ x,
    const float* __restrict__ Wih0, const float* __restrict__ Whh0,
    const float* __restrict__ bih0, const float* __restrict__ bhh0,
    const float* __restrict__ Whr0,
    const float* __restrict__ Wihs, const float* __restrict__ Whhs,
    const float* __restrict__ bihs, const float* __restrict__ bhhs,
    const float* __restrict__ Whrs,
    float* __restrict__ out,
    unsigned* __restrict__ yP, unsigned* __restrict__ hP,
    unsigned* __restrict__ cnt)
{
  __shared__ short sWh[32 * WSTRIDE];   // 49664 B
  __shared__ short sWl[32 * WSTRIDE];   // 49664 B
  __shared__ float sBias[32];
  __shared__ float sG[64 * 32];         // 8192 B

  const int tid  = threadIdx.x;
  const int wg   = blockIdx.x;
  const int lane = tid & 63;
  const int wave = tid >> 6;
  unsigned ep = 0;

  // mfma_f32_32x32x16_bf16 lane geometry:
  //   A[m][k]: m = lane&31 (+ wave*32), k = (lane>>5)*8 + j
  //   B[k][n] = W[n][k]: n = lane&31
  //   D: col = lane&31, row = (reg&3) + 8*(reg>>2) + 4*(lane>>5)
  const int m1  = wave * 32 + (lane & 31);  // batch row
  const int n1  = lane & 31;                // local gate row
  const int kh1 = (lane >> 5) * 8;

  for (int l = 0; l < 4; ++l) {
    const int K1 = (l == 0) ? D_ : P_;
    const float* Wih = (l == 0) ? Wih0 : Wihs + (size_t)(l - 1) * 4096 * 256;
    const float* Whh = (l == 0) ? Whh0 : Whhs + (size_t)(l - 1) * 4096 * 256;
    const float* bih = (l == 0) ? bih0 : bihs + (size_t)(l - 1) * 4096;
    const float* bhh = (l == 0) ? bhh0 : bhhs + (size_t)(l - 1) * 4096;
    const float* Whr = (l == 0) ? Whr0 : Whrs + (size_t)(l - 1) * 256 * 1024;

    // ---- stage weight slice (split hi/lo) + bias into LDS ----
    {
      const int cpr = (K1 + P_) >> 3;
      for (int c = tid; c < 32 * cpr; c += NTHR) {
        int r = c / cpr;
        int k = (c - r * cpr) * 8;
        int R = (r & 3) * H_ + wg * UPW + (r >> 2);   // gate*H + unit
        const float* src = (k < K1) ? (Wih + (size_t)R * K1 + k)
                                    : (Whh + (size_t)R * P_ + (k - K1));
        short8 hi, lo;
        split8(src, hi, lo);
        *(short8*)&sWh[r * WSTRIDE + k] = hi;
        *(short8*)&sWl[r * WSTRIDE + k] = lo;
      }
      if (tid < 32) {
        int r = tid;
        int R = (r & 3) * H_ + wg * UPW + (r >> 2);
        sBias[r] = bih[R] + bhh[R];
      }
      __syncthreads();
      // Once per layer: drop any stale y[t]-input lines cached during the
      // previous layer (in-place y overwrite + no cross-XCD snooping).
      __threadfence();
    }

    float cs0 = 0.f, cs1 = 0.f, cs2 = 0.f, cs3 = 0.f;

    for (int t = 0; t < T_; ++t) {
      // ================= phase 1: gates + state update =================
      f32x16 acc = {};
      {
        const short* bwh = &sWh[n1 * WSTRIDE + kh1];
        const short* bwl = &sWl[n1 * WSTRIDE + kh1];
        if (l == 0) {
          const float* axf = x + ((size_t)m1 * T_ + t) * D_ + kh1;
#pragma unroll 4
          for (int k0 = 0; k0 < D_; k0 += 16) {
            short8 ah, al;
            split8(axf + k0, ah, al);
            short8 bh = *(const short8*)(bwh + k0);
            short8 bl = *(const short8*)(bwl + k0);
            acc = __builtin_amdgcn_mfma_f32_32x32x16_bf16(ah, bh, acc, 0, 0, 0);
            acc = __builtin_amdgcn_mfma_f32_32x32x16_bf16(ah, bl, acc, 0, 0, 0);
            acc = __builtin_amdgcn_mfma_f32_32x32x16_bf16(al, bh, acc, 0, 0, 0);
          }
        } else {
          // input y[t] from previous layer: normal cached loads
          const unsigned* ypi = yP + ((size_t)t * B_ + m1) * P_ + kh1;
#pragma unroll 4
          for (int k0 = 0; k0 < P_; k0 += 16) {
            short8 ah, al;
            unpack_c8(ypi + k0, ah, al);
            short8 bh = *(const short8*)(bwh + k0);
            short8 bl = *(const short8*)(bwl + k0);
            acc = __builtin_amdgcn_mfma_f32_32x32x16_bf16(ah, bh, acc, 0, 0, 0);
            acc = __builtin_amdgcn_mfma_f32_32x32x16_bf16(ah, bl, acc, 0, 0, 0);
            acc = __builtin_amdgcn_mfma_f32_32x32x16_bf16(al, bh, acc, 0, 0, 0);
          }
        }
        if (t > 0) {   // recurrent y[t-1] (this layer's own, 1 epoch old): sc1
          const unsigned* ypr = yP + ((size_t)(t - 1) * B_ + m1) * P_ + kh1;
          const short* bhh_h = bwh + K1;
          const short* bhh_l = bwl + K1;
#pragma unroll 4
          for (int k0 = 0; k0 < P_; k0 += 16) {
            short8 ah, al;
            unpack_a8(ypr + k0, ah, al);
            short8 bh = *(const short8*)(bhh_h + k0);
            short8 bl = *(const short8*)(bhh_l + k0);
            acc = __builtin_amdgcn_mfma_f32_32x32x16_bf16(ah, bh, acc, 0, 0, 0);
            acc = __builtin_amdgcn_mfma_f32_32x32x16_bf16(ah, bl, acc, 0, 0, 0);
            acc = __builtin_amdgcn_mfma_f32_32x32x16_bf16(al, bh, acc, 0, 0, 0);
          }
        }
      }
#pragma unroll
      for (int r = 0; r < 16; ++r) {
        int mrow = (r & 3) + 8 * (r >> 2) + 4 * (lane >> 5) + wave * 32;
        sG[mrow * 32 + n1] = acc[r];
      }
      __syncthreads();
      {
        const int b  = tid >> 1;
        const int u4 = (tid & 1) * 4;
        const float* gp = &sG[b * 32];
        float cr[4] = {cs0, cs1, cs2, cs3};
        unsigned pw[4];
#pragma unroll
        for (int j = 0; j < 4; ++j) {
          int u = u4 + j;
          float ii = sigm(gp[u * 4 + 0] + sBias[u * 4 + 0]);
          float ff = sigm(gp[u * 4 + 1] + sBias[u * 4 + 1]);
          float gg = tanh_f(gp[u * 4 + 2] + sBias[u * 4 + 2]);
          float oo = sigm(gp[u * 4 + 3] + sBias[u * 4 + 3]);
          float cv = ff * cr[j] + ii * gg;
          cr[j] = cv;
          pw[j] = packf(oo * tanh_f(cv));
        }
        cs0 = cr[0]; cs1 = cr[1]; cs2 = cr[2]; cs3 = cr[3];
        size_t ho = (size_t)b * H_ + wg * UPW + u4;
        unsigned long long q0 = (unsigned long long)pw[0] | ((unsigned long long)pw[1] << 32);
        unsigned long long q1 = (unsigned long long)pw[2] | ((unsigned long long)pw[3] << 32);
        __hip_atomic_store((unsigned long long*)&hP[ho], q0,
                           __ATOMIC_RELAXED, __HIP_MEMORY_SCOPE_AGENT);
        __hip_atomic_store((unsigned long long*)&hP[ho + 2], q1,
                           __ATOMIC_RELAXED, __HIP_MEMORY_SCOPE_AGENT);
      }
      ep++; gbar(cnt, NWG * ep);

      // ================= phase 2: projection y_t = h @ Whr^T ===========
      // mfma_f32_16x16x32_bf16: A m = lane&15, k = (lane>>4)*8 + j;
      // B n = lane&15 (Whr row), same k; D col = lane&15, row = quad*4+reg.
      if (wg < 64 && wave == 0) {
        const int m0  = (wg >> 4) * 16;
        const int n0  = (wg & 15) * 16;
        const int l16 = lane & 15;
        const int kh2 = (lane >> 4) * 8;
        const unsigned* ahp = hP + (size_t)(m0 + l16) * H_ + kh2;
        const float*    bwf = Whr + (size_t)(n0 + l16) * H_ + kh2;  // cached
        f32x4 a4 = {};
#pragma unroll 4
        for (int k0 = 0; k0 < H_; k0 += 32) {
          short8 Ah, Al, Bh, Bl;
          unpack_a8(ahp + k0, Ah, Al);
          split8(bwf + k0, Bh, Bl);
          a4 = __builtin_amdgcn_mfma_f32_16x16x32_bf16(Ah, Bh, a4, 0, 0, 0);
          a4 = __builtin_amdgcn_mfma_f32_16x16x32_bf16(Ah, Bl, a4, 0, 0, 0);
          a4 = __builtin_amdgcn_mfma_f32_16x16x32_bf16(Al, Bh, a4, 0, 0, 0);
        }
#pragma unroll
        for (int r = 0; r < 4; ++r) {
          int mm  = m0 + (lane >> 4) * 4 + r;
          int col = n0 + l16;
          float v = a4[r];
          __hip_atomic_store(&yP[((size_t)t * B_ + mm) * P_ + col], packf(v),
                             __ATOMIC_RELAXED, __HIP_MEMORY_SCOPE_AGENT);
          if (l == 3 && t == T_ - 1) out[mm * P_ + col] = v;
        }
      }
      ep++; gbar(cnt, NWG * ep);
    }
  }
}

extern "C" void kernel_launch(void* const* d_in, const int* in_sizes, int n_in,
                              void* d_out, int out_size, void* d_ws, size_t ws_size,
                              hipStream_t stream) {
  const float* x    = (const float*)d_in[0];
  const float* Wih0 = (const float*)d_in[1];
  const float* Whh0 = (const float*)d_in[2];
  const float* bih0 = (const float*)d_in[3];
  const float* bhh0 = (const float*)d_in[4];
  const float* Whr0 = (const float*)d_in[5];
  const float* Wihs = (const float*)d_in[6];
  const float* Whhs = (const float*)d_in[7];
  const float* bihs = (const float*)d_in[8];
  const float* bhhs = (const float*)d_in[9];
  const float* Whrs = (const float*)d_in[10];
  float* out = (float*)d_out;

  char* ws = (char*)d_ws;
  unsigned* cnt = (unsigned*)ws;                    // 1 KB
  unsigned* yP  = (unsigned*)(ws + 1024);           // 16 MB (T*B*P u32)
  unsigned* hP  = (unsigned*)(ws + 1024 + 16777216); // 256 KB (B*H u32)

  (void)hipMemsetAsync(d_ws, 0, 256, stream);   // zero barrier counter

  void* args[] = {&x, &Wih0, &Whh0, &bih0, &bhh0, &Whr0,
                  &Wihs, &Whhs, &bihs, &bhhs, &Whrs,
                  &out, &yP, &hP, &cnt};
  (void)hipLaunchCooperativeKernel((void*)lstm_kernel, dim3(NWG), dim3(NTHR),
                                   args, 0, stream);
}

// Round 6
// 23830.775 us; speedup vs baseline: 2.0867x; 1.2055x over previous
//
#include <hip/hip_runtime.h>
#include <cstdint>
#include <cstddef>

// 4-layer projected LSTM. B=64 T=256 D=512 H=1024 P=256. fp32 in/out.
// Split-bf16 (hi+lo) MFMA operands, 3 MFMAs per product (absmax 6e-5).
//
// Round-6 (from 28.7 ms, epoch=13.6us, all pipes <3%):
//  1. Striped grid barrier: 32 padded counters (4 adds each) instead of 128
//     serialized RMWs on one L3 line. Poll = 32 pipelined loads.
//  2. 3 independent accumulator chains (hh/hl/lh) in both GEMMs: at 1 WG/CU
//     (LDS-bound) there is no TLP, so a single dependent-MFMA chain exposes
//     full latency; 3 chains pipeline the MFMA unit.
//  3. Phase 2 uses both waves (K=1024 split 512/512 + LDS reduce).
//  4. Ping-pong y buffers (if ws_size allows): recurrent y[t-1] reads become
//     normal cached dwordx4 loads (sc1 writes leave no stale L2 copies; lines
//     are read-once per layer and L2-shared within an XCD). One __threadfence
//     per layer start invalidates cross-layer/prior-launch aliases.
//     Fallback (small ws): round-5 in-place y + sc1 recurrent reads.
// Workspace: [cnt 4K][hP 256K][Y0 16M][Y1 16M] ~= 33.8 MB (fallback: Y1=Y0).

#define B_ 64
#define T_ 256
#define D_ 512
#define H_ 1024
#define P_ 256
#define NWG 128
#define NTHR 128
#define UPW 8
#define WSTRIDE 776    // 768 + 8 pad (16B-aligned rows)

using short8  = __attribute__((ext_vector_type(8))) short;
using f32x16  = __attribute__((ext_vector_type(16))) float;
using f32x4   = __attribute__((ext_vector_type(4))) float;

__device__ inline float bf2f(short s) {
  unsigned u = ((unsigned)(unsigned short)s) << 16;
  return __builtin_bit_cast(float, u);
}
__device__ inline unsigned short f2bf(float f) {
  unsigned u = __builtin_bit_cast(unsigned, f);
  u += 0x7fffu + ((u >> 16) & 1u);   // RTNE
  return (unsigned short)(u >> 16);
}
__device__ inline void split1(float v, short& hi, short& lo) {
  unsigned short h = f2bf(v);
  hi = (short)h;
  lo = (short)f2bf(v - bf2f((short)h));
}
__device__ inline unsigned packf(float v) {
  short h, l;
  split1(v, h, l);
  return (unsigned)(unsigned short)h | ((unsigned)(unsigned short)l << 16);
}
__device__ inline void split8(const float* p, short8& hi, short8& lo) {
  float4 a = *(const float4*)p;
  float4 b = *(const float4*)(p + 4);
  float v[8] = {a.x, a.y, a.z, a.w, b.x, b.y, b.z, b.w};
#pragma unroll
  for (int i = 0; i < 8; ++i) {
    short h, l;
    split1(v[i], h, l);
    hi[i] = h; lo[i] = l;
  }
}
// 8 packed elems via normal cached loads
__device__ inline void unpack_c8(const unsigned* p, short8& hi, short8& lo) {
  uint4 a = *(const uint4*)p;
  uint4 b = *(const uint4*)(p + 4);
  unsigned w[8] = {a.x, a.y, a.z, a.w, b.x, b.y, b.z, b.w};
#pragma unroll
  for (int i = 0; i < 8; ++i) {
    hi[i] = (short)(w[i] & 0xffff);
    lo[i] = (short)(w[i] >> 16);
  }
}
// 8 packed elems via agent-coherent (L2-bypassing) loads
__device__ inline void unpack_a8(const unsigned* p, short8& hi, short8& lo) {
#pragma unroll
  for (int i = 0; i < 4; ++i) {
    unsigned long long v = __hip_atomic_load((const unsigned long long*)p + i,
                                             __ATOMIC_RELAXED, __HIP_MEMORY_SCOPE_AGENT);
    unsigned w0 = (unsigned)v, w1 = (unsigned)(v >> 32);
    hi[2 * i]     = (short)(w0 & 0xffff);
    lo[2 * i]     = (short)(w0 >> 16);
    hi[2 * i + 1] = (short)(w1 & 0xffff);
    lo[2 * i + 1] = (short)(w1 >> 16);
  }
}
__device__ inline float sigm(float x)   { return 1.f / (1.f + __expf(-x)); }
__device__ inline float tanh_f(float x) { return 1.f - 2.f / (__expf(2.f * x) + 1.f); }

// Striped fence-free grid barrier: 32 counters, 64B apart. 4 arrivals per
// counter (parallel across stripes); poll sums 32 pipelined L3 loads.
#define NCNT 32
__device__ inline void gbar(unsigned* cnt, unsigned target) {
  __syncthreads();   // drains vmcnt: all sc1 stores globally visible
  if (threadIdx.x == 0) {
    __hip_atomic_fetch_add(&cnt[(blockIdx.x & (NCNT - 1)) * 16], 1u,
                           __ATOMIC_RELAXED, __HIP_MEMORY_SCOPE_AGENT);
    for (;;) {
      unsigned s = 0;
#pragma unroll
      for (int i = 0; i < NCNT; ++i)
        s += __hip_atomic_load(&cnt[i * 16], __ATOMIC_RELAXED,
                               __HIP_MEMORY_SCOPE_AGENT);
      if (s >= target) break;
      __builtin_amdgcn_s_sleep(2);
    }
  }
  __syncthreads();
}

__global__ __launch_bounds__(NTHR) void lstm_kernel(
    const float* __restrict__ x,
    const float* __restrict__ Wih0, const float* __restrict__ Whh0,
    const float* __restrict__ bih0, const float* __restrict__ bhh0,
    const float* __restrict__ Whr0,
    const float* __restrict__ Wihs, const float* __restrict__ Whhs,
    const float* __restrict__ bihs, const float* __restrict__ bhhs,
    const float* __restrict__ Whrs,
    float* __restrict__ out,
    unsigned* __restrict__ Y0, unsigned* __restrict__ Y1,
    unsigned* __restrict__ hP, unsigned* __restrict__ cnt)
{
  __shared__ short sWh[32 * WSTRIDE];   // 49664 B
  __shared__ short sWl[32 * WSTRIDE];   // 49664 B
  __shared__ float sBias[32];
  __shared__ float sG[64 * 32];         // 8192 B
  __shared__ float sRed[64 * 4];        // 1024 B (phase-2 cross-wave reduce)

  const int tid  = threadIdx.x;
  const int wg   = blockIdx.x;
  const int lane = tid & 63;
  const int wave = tid >> 6;
  const bool pp  = (Y0 != Y1);          // ping-pong mode
  unsigned ep = 0;

  // mfma_f32_32x32x16_bf16 lane geometry:
  //   A[m][k]: m = lane&31 (+ wave*32), k = (lane>>5)*8 + j
  //   B[k][n] = W[n][k]: n = lane&31
  //   D: col = lane&31, row = (reg&3) + 8*(reg>>2) + 4*(lane>>5)
  const int m1  = wave * 32 + (lane & 31);  // batch row
  const int n1  = lane & 31;                // local gate row
  const int kh1 = (lane >> 5) * 8;

  for (int l = 0; l < 4; ++l) {
    const int K1 = (l == 0) ? D_ : P_;
    const float* Wih = (l == 0) ? Wih0 : Wihs + (size_t)(l - 1) * 4096 * 256;
    const float* Whh = (l == 0) ? Whh0 : Whhs + (size_t)(l - 1) * 4096 * 256;
    const float* bih = (l == 0) ? bih0 : bihs + (size_t)(l - 1) * 4096;
    const float* bhh = (l == 0) ? bhh0 : bhhs + (size_t)(l - 1) * 4096;
    const float* Whr = (l == 0) ? Whr0 : Whrs + (size_t)(l - 1) * 256 * 1024;
    // ping-pong: l0: x->Y0, l1: Y0->Y1, l2: Y1->Y0, l3: Y0->Y1
    const unsigned* yIn = (l & 1) ? Y0 : Y1;   // unused for l==0
    unsigned*       yOut = (l & 1) ? Y1 : Y0;

    // ---- stage weight slice (split hi/lo) + bias into LDS ----
    {
      const int cpr = (K1 + P_) >> 3;
      for (int c = tid; c < 32 * cpr; c += NTHR) {
        int r = c / cpr;
        int k = (c - r * cpr) * 8;
        int R = (r & 3) * H_ + wg * UPW + (r >> 2);   // gate*H + unit
        const float* src = (k < K1) ? (Wih + (size_t)R * K1 + k)
                                    : (Whh + (size_t)R * P_ + (k - K1));
        short8 hi, lo;
        split8(src, hi, lo);
        *(short8*)&sWh[r * WSTRIDE + k] = hi;
        *(short8*)&sWl[r * WSTRIDE + k] = lo;
      }
      if (tid < 32) {
        int r = tid;
        int R = (r & 3) * H_ + wg * UPW + (r >> 2);
        sBias[r] = bih[R] + bhh[R];
      }
      __syncthreads();
      // Per-layer L2 invalidate: kills stale lines from the buffer's use two
      // layers ago and from the previous graph-replay launch.
      __threadfence();
    }

    float cs0 = 0.f, cs1 = 0.f, cs2 = 0.f, cs3 = 0.f;

    for (int t = 0; t < T_; ++t) {
      // ================= phase 1: gates + state update =================
      // 3 independent accumulator chains (hh / hl / lh) -> MFMA pipelining.
      f32x16 ahh = {}, ahl = {}, alh = {};
      {
        const short* bwh = &sWh[n1 * WSTRIDE + kh1];
        const short* bwl = &sWl[n1 * WSTRIDE + kh1];
        if (l == 0) {
          const float* axf = x + ((size_t)m1 * T_ + t) * D_ + kh1;
#pragma unroll 4
          for (int k0 = 0; k0 < D_; k0 += 16) {
            short8 Ah, Al;
            split8(axf + k0, Ah, Al);
            short8 Bh = *(const short8*)(bwh + k0);
            short8 Bl = *(const short8*)(bwl + k0);
            ahh = __builtin_amdgcn_mfma_f32_32x32x16_bf16(Ah, Bh, ahh, 0, 0, 0);
            ahl = __builtin_amdgcn_mfma_f32_32x32x16_bf16(Ah, Bl, ahl, 0, 0, 0);
            alh = __builtin_amdgcn_mfma_f32_32x32x16_bf16(Al, Bh, alh, 0, 0, 0);
          }
        } else {
          const unsigned* ypi = yIn + ((size_t)t * B_ + m1) * P_ + kh1;
#pragma unroll 4
          for (int k0 = 0; k0 < P_; k0 += 16) {
            short8 Ah, Al;
            unpack_c8(ypi + k0, Ah, Al);
            short8 Bh = *(const short8*)(bwh + k0);
            short8 Bl = *(const short8*)(bwl + k0);
            ahh = __builtin_amdgcn_mfma_f32_32x32x16_bf16(Ah, Bh, ahh, 0, 0, 0);
            ahl = __builtin_amdgcn_mfma_f32_32x32x16_bf16(Ah, Bl, ahl, 0, 0, 0);
            alh = __builtin_amdgcn_mfma_f32_32x32x16_bf16(Al, Bh, alh, 0, 0, 0);
          }
        }
        if (t > 0) {   // recurrent y[t-1] (own output, 1 epoch old)
          const unsigned* ypr = yOut + ((size_t)(t - 1) * B_ + m1) * P_ + kh1;
          const short* bhh_h = bwh + K1;
          const short* bhh_l = bwl + K1;
#pragma unroll 4
          for (int k0 = 0; k0 < P_; k0 += 16) {
            short8 Ah, Al;
            if (pp) unpack_c8(ypr + k0, Ah, Al);   // cached: sc1-written, read-once
            else    unpack_a8(ypr + k0, Ah, Al);   // in-place fallback: coherent
            short8 Bh = *(const short8*)(bhh_h + k0);
            short8 Bl = *(const short8*)(bhh_l + k0);
            ahh = __builtin_amdgcn_mfma_f32_32x32x16_bf16(Ah, Bh, ahh, 0, 0, 0);
            ahl = __builtin_amdgcn_mfma_f32_32x32x16_bf16(Ah, Bl, ahl, 0, 0, 0);
            alh = __builtin_amdgcn_mfma_f32_32x32x16_bf16(Al, Bh, alh, 0, 0, 0);
          }
        }
      }
#pragma unroll
      for (int r = 0; r < 16; ++r) {
        int mrow = (r & 3) + 8 * (r >> 2) + 4 * (lane >> 5) + wave * 32;
        sG[mrow * 32 + n1] = ahh[r] + ahl[r] + alh[r];
      }
      __syncthreads();
      {
        const int b  = tid >> 1;
        const int u4 = (tid & 1) * 4;
        const float* gp = &sG[b * 32];
        float cr[4] = {cs0, cs1, cs2, cs3};
        unsigned pw[4];
#pragma unroll
        for (int j = 0; j < 4; ++j) {
          int u = u4 + j;
          float ii = sigm(gp[u * 4 + 0] + sBias[u * 4 + 0]);
          float ff = sigm(gp[u * 4 + 1] + sBias[u * 4 + 1]);
          float gg = tanh_f(gp[u * 4 + 2] + sBias[u * 4 + 2]);
          float oo = sigm(gp[u * 4 + 3] + sBias[u * 4 + 3]);
          float cv = ff * cr[j] + ii * gg;
          cr[j] = cv;
          pw[j] = packf(oo * tanh_f(cv));
        }
        cs0 = cr[0]; cs1 = cr[1]; cs2 = cr[2]; cs3 = cr[3];
        size_t ho = (size_t)b * H_ + wg * UPW + u4;
        unsigned long long q0 = (unsigned long long)pw[0] | ((unsigned long long)pw[1] << 32);
        unsigned long long q1 = (unsigned long long)pw[2] | ((unsigned long long)pw[3] << 32);
        __hip_atomic_store((unsigned long long*)&hP[ho], q0,
                           __ATOMIC_RELAXED, __HIP_MEMORY_SCOPE_AGENT);
        __hip_atomic_store((unsigned long long*)&hP[ho + 2], q1,
                           __ATOMIC_RELAXED, __HIP_MEMORY_SCOPE_AGENT);
      }
      ep++; gbar(cnt, NWG * ep);

      // ================= phase 2: projection y_t = h @ Whr^T ===========
      // WGs 0..63, BOTH waves: wave w handles K in [w*512, w*512+512).
      // mfma_f32_16x16x32_bf16: A m = lane&15, k = (lane>>4)*8 + j;
      // B n = lane&15 (Whr row); D col = lane&15, row = quad*4+reg.
      if (wg < 64) {
        const int m0  = (wg >> 4) * 16;
        const int n0  = (wg & 15) * 16;
        const int l16 = lane & 15;
        const int kh2 = (lane >> 4) * 8 + wave * 512;
        const unsigned* ahp = hP + (size_t)(m0 + l16) * H_ + kh2;   // sc1
        const float*    bwf = Whr + (size_t)(n0 + l16) * H_ + kh2;  // cached
        f32x4 phh = {}, phl = {}, plh = {};
#pragma unroll 4
        for (int k0 = 0; k0 < 512; k0 += 32) {
          short8 Ah, Al, Bh, Bl;
          unpack_a8(ahp + k0, Ah, Al);
          split8(bwf + k0, Bh, Bl);
          phh = __builtin_amdgcn_mfma_f32_16x16x32_bf16(Ah, Bh, phh, 0, 0, 0);
          phl = __builtin_amdgcn_mfma_f32_16x16x32_bf16(Ah, Bl, phl, 0, 0, 0);
          plh = __builtin_amdgcn_mfma_f32_16x16x32_bf16(Al, Bh, plh, 0, 0, 0);
        }
        f32x4 a4;
#pragma unroll
        for (int r = 0; r < 4; ++r) a4[r] = phh[r] + phl[r] + plh[r];
        if (wave == 1) *(f32x4*)&sRed[lane * 4] = a4;
        __syncthreads();
        if (wave == 0) {
          f32x4 o = *(const f32x4*)&sRed[lane * 4];
#pragma unroll
          for (int r = 0; r < 4; ++r) {
            int mm  = m0 + (lane >> 4) * 4 + r;
            int col = n0 + l16;
            float v = a4[r] + o[r];
            __hip_atomic_store(&yOut[((size_t)t * B_ + mm) * P_ + col], packf(v),
                               __ATOMIC_RELAXED, __HIP_MEMORY_SCOPE_AGENT);
            if (l == 3 && t == T_ - 1) out[mm * P_ + col] = v;
          }
        }
      }
      ep++; gbar(cnt, NWG * ep);
    }
  }
}

extern "C" void kernel_launch(void* const* d_in, const int* in_sizes, int n_in,
                              void* d_out, int out_size, void* d_ws, size_t ws_size,
                              hipStream_t stream) {
  const float* x    = (const float*)d_in[0];
  const float* Wih0 = (const float*)d_in[1];
  const float* Whh0 = (const float*)d_in[2];
  const float* bih0 = (const float*)d_in[3];
  const float* bhh0 = (const float*)d_in[4];
  const float* Whr0 = (const float*)d_in[5];
  const float* Wihs = (const float*)d_in[6];
  const float* Whhs = (const float*)d_in[7];
  const float* bihs = (const float*)d_in[8];
  const float* bhhs = (const float*)d_in[9];
  const float* Whrs = (const float*)d_in[10];
  float* out = (float*)d_out;

  char* ws = (char*)d_ws;
  unsigned* cnt = (unsigned*)ws;                       // 4 KB (32 counters, 64B apart)
  unsigned* hP  = (unsigned*)(ws + 4096);              // 256 KB (B*H u32)
  unsigned* Y0  = (unsigned*)(ws + 4096 + 262144);     // 16 MB (T*B*P u32)
  // ping-pong second buffer if workspace allows, else in-place fallback
  const size_t need_pp = 4096 + 262144 + 2u * 16777216;
  unsigned* Y1 = (ws_size >= need_pp) ? (unsigned*)(ws + 4096 + 262144 + 16777216)
                                      : Y0;

  (void)hipMemsetAsync(d_ws, 0, 4096, stream);   // zero barrier counters

  void* args[] = {&x, &Wih0, &Whh0, &bih0, &bhh0, &Whr0,
                  &Wihs, &Whhs, &bihs, &bhhs, &Whrs,
                  &out, &Y0, &Y1, &hP, &cnt};
  (void)hipLaunchCooperativeKernel((void*)lstm_kernel, dim3(NWG), dim3(NTHR),
                                   args, 0, stream);
}